// Round 3
// baseline (94.935 us; speedup 1.0000x reference)
//
#include <hip/hip_runtime.h>
#include <math.h>
#include <stdint.h>

// ContrastiveLoss: N=8192, C=512, NC=100, MARGIN=1.0
// loss = (sum_{i!=j,same} d_ij + sum_{i!=j,diff} max(0, 1-sqrt(d_ij))^2) / (2*N*(N-1))
// d_ij = |xi|^2+|xj|^2-2 xi.xj (clamped at 0).
//
// Round 3: m97-structure Gram tile — global_load_lds(16B) direct-to-LDS staging,
// LINEAR LDS (swizzle is null at 2-phase per regime-gate), 128x128 triangular
// tiles, BK=64, 4 waves, fused loss epilogue, 32KB LDS (5 blocks/CU).
// cvt+sq fused into one pass over the fp32 input.

static constexpr int   Nn  = 8192;
static constexpr int   Cc  = 512;
static constexpr float MRG = 1.0f;

// ---- mfma config ----
static constexpr int BM2     = 128;
static constexpr int BK2     = 64;
static constexpr int NBLK2   = Nn / BM2;                  // 64
static constexpr int NPAIRS2 = NBLK2 * (NBLK2 + 1) / 2;   // 2080

// ---- fp32 fallback config ----
static constexpr int BM1     = 64;
static constexpr int BK1     = 32;
static constexpr int NBLK1   = Nn / BM1;                  // 128
static constexpr int NPAIRS1 = NBLK1 * (NBLK1 + 1) / 2;   // 8256
static constexpr int LSTR    = 68;

typedef __attribute__((ext_vector_type(8))) short short8v;  // 8 bf16 (4 VGPRs)
typedef __attribute__((ext_vector_type(4))) float f32x4;
typedef unsigned int u32;

// CK-proven cast pattern: flat->AS1 / AS3 via reinterpret (no addrspacecast)
static __device__ inline void gload_lds16(const void* g, void* lds) {
    __builtin_amdgcn_global_load_lds(
        (const __attribute__((address_space(1))) u32*)g,
        (__attribute__((address_space(3))) u32*)(uintptr_t)(
            (char*)lds - (char*)nullptr ? (uintptr_t)lds : (uintptr_t)lds),
        16, 0, 0);
}

// ---------------------------------------------------------------- fp32 -> bf16 (RNE)
static __device__ inline unsigned short f2bf(float x) {
    unsigned u = __float_as_uint(x);
    unsigned rnd = 0x7FFFu + ((u >> 16) & 1u);
    return (unsigned short)((u + rnd) >> 16);
}

// ---------------------------------------------------------------- fused cvt + |x|^2
__global__ __launch_bounds__(256) void cvtsq_kernel(const float* __restrict__ f,
                                                    unsigned short* __restrict__ fb,
                                                    float* __restrict__ sq) {
    const int wave = threadIdx.x >> 6;
    const int lane = threadIdx.x & 63;
    const int row  = blockIdx.x * 4 + wave;
    const float4* rp = reinterpret_cast<const float4*>(f + (size_t)row * Cc);
    float4 v0 = rp[lane * 2 + 0];
    float4 v1 = rp[lane * 2 + 1];
    float s = v0.x * v0.x + v0.y * v0.y + v0.z * v0.z + v0.w * v0.w +
              v1.x * v1.x + v1.y * v1.y + v1.z * v1.z + v1.w * v1.w;
    short8v o;
    o[0] = (short)f2bf(v0.x); o[1] = (short)f2bf(v0.y);
    o[2] = (short)f2bf(v0.z); o[3] = (short)f2bf(v0.w);
    o[4] = (short)f2bf(v1.x); o[5] = (short)f2bf(v1.y);
    o[6] = (short)f2bf(v1.z); o[7] = (short)f2bf(v1.w);
    *reinterpret_cast<short8v*>(fb + (size_t)row * Cc + lane * 8) = o;
    #pragma unroll
    for (int off = 32; off > 0; off >>= 1) s += __shfl_down(s, off, 64);
    if (lane == 0) sq[row] = s;
}

// ---------------------------------------------------------------- MFMA pairwise tile
__global__ __launch_bounds__(256) void pair_mfma(const unsigned short* __restrict__ fb,
                                                 const int* __restrict__ tgt,
                                                 const float* __restrict__ sq,
                                                 double* __restrict__ partials) {
    // linear block id -> (br, bc), br <= bc (upper triangle of 64x64 blocks)
    int rem = blockIdx.x, br = 0;
    while (rem >= NBLK2 - br) { rem -= NBLK2 - br; ++br; }
    const int bc = br + rem;

    __shared__ unsigned short As[BM2 * BK2];   // [row][k], LINEAR (16 KB)
    __shared__ unsigned short Bs[BM2 * BK2];   // 16 KB  -> total exactly 32 KB

    const int tid  = threadIdx.x;
    const int lane = tid & 63;
    const int wid  = tid >> 6;
    const int wr   = wid >> 1;     // wave row 0..1 (64-row slab)
    const int wc   = wid & 1;      // wave col 0..1 (64-col slab)

    const unsigned short* ga = fb + (size_t)(br * BM2) * Cc;
    const unsigned short* gb = fb + (size_t)(bc * BM2) * Cc;

    // staging geometry: one gload_lds = 64 lanes x 16B = 1KB = 8 rows of [64]bf16
    const int crow = lane >> 3;        // row within 8-row chunk
    const int ckb  = (lane & 7) * 8;   // bf16 offset within row (8 elems = 16B)

    const f32x4 zero = {0.f, 0.f, 0.f, 0.f};
    f32x4 acc[4][4];
    #pragma unroll
    for (int mf = 0; mf < 4; ++mf)
        #pragma unroll
        for (int nf = 0; nf < 4; ++nf) acc[mf][nf] = zero;

    for (int k0 = 0; k0 < Cc; k0 += BK2) {
        __syncthreads();   // previous chunk's compute done before overwrite
        // wave wid stages chunks 4*wid .. 4*wid+3 of both A and B tiles
        #pragma unroll
        for (int c4 = 0; c4 < 4; ++c4) {
            const int chunk = wid * 4 + c4;            // 0..15
            const int row   = chunk * 8 + crow;        // tile row
            const size_t goff = (size_t)row * Cc + k0 + ckb;
            gload_lds16(ga + goff, (char*)As + chunk * 1024);
            gload_lds16(gb + goff, (char*)Bs + chunk * 1024);
        }
        __syncthreads();   // compiler drains vmcnt(0) before s_barrier

        #pragma unroll
        for (int ks = 0; ks < 2; ++ks) {
            short8v a[4], b[4];
            #pragma unroll
            for (int mf = 0; mf < 4; ++mf) {
                const int row = wr * 64 + mf * 16 + (lane & 15);
                a[mf] = *reinterpret_cast<const short8v*>(
                    (const char*)As + row * 128 + ks * 64 + (lane >> 4) * 16);
            }
            #pragma unroll
            for (int nf = 0; nf < 4; ++nf) {
                const int row = wc * 64 + nf * 16 + (lane & 15);
                b[nf] = *reinterpret_cast<const short8v*>(
                    (const char*)Bs + row * 128 + ks * 64 + (lane >> 4) * 16);
            }
            #pragma unroll
            for (int mf = 0; mf < 4; ++mf)
                #pragma unroll
                for (int nf = 0; nf < 4; ++nf)
                    acc[mf][nf] = __builtin_amdgcn_mfma_f32_16x16x32_bf16(
                        a[mf], b[nf], acc[mf][nf], 0, 0, 0);
        }
    }

    // ------------------------------------------------------------ fused loss epilogue
    // C/D layout: col = lane&15, row = (lane>>4)*4 + reg  [m89/m91]
    const int gi0 = br * BM2 + wr * 64;
    const int gj0 = bc * BM2 + wc * 64;

    float sqi[16]; int ti[16];
    #pragma unroll
    for (int mf = 0; mf < 4; ++mf)
        #pragma unroll
        for (int j = 0; j < 4; ++j) {
            const int r = gi0 + mf * 16 + (lane >> 4) * 4 + j;
            sqi[mf * 4 + j] = sq[r];
            ti[mf * 4 + j]  = tgt[r];
        }
    float sqj[4]; int tj[4];
    #pragma unroll
    for (int nf = 0; nf < 4; ++nf) {
        const int c = gj0 + nf * 16 + (lane & 15);
        sqj[nf] = sq[c];
        tj[nf]  = tgt[c];
    }

    float pos = 0.f, neg = 0.f;
    #pragma unroll
    for (int mf = 0; mf < 4; ++mf)
        #pragma unroll
        for (int nf = 0; nf < 4; ++nf)
            #pragma unroll
            for (int j = 0; j < 4; ++j) {
                const int r = gi0 + mf * 16 + (lane >> 4) * 4 + j;
                const int c = gj0 + nf * 16 + (lane & 15);
                const float d = fmaxf(sqi[mf * 4 + j] + sqj[nf] - 2.0f * acc[mf][nf][j], 0.0f);
                if (r != c) {
                    if (ti[mf * 4 + j] == tj[nf]) {
                        pos += d;
                    } else if (d < 1.0f) {        // hinge active iff sqrt(d) < margin
                        const float t = MRG - sqrtf(d);
                        neg += t * t;
                    }
                }
            }

    // block reduction reusing As (all compute done)
    __syncthreads();
    float* red = reinterpret_cast<float*>(As);
    const float w = (br == bc) ? 1.0f : 2.0f;
    red[tid] = w * (pos + neg);
    __syncthreads();
    #pragma unroll
    for (int st = 128; st > 0; st >>= 1) {
        if (tid < st) red[tid] += red[tid + st];
        __syncthreads();
    }
    if (tid == 0) partials[blockIdx.x] = (double)red[0];
}

// ---------------------------------------------------------------- fp32 fallback (round 1)
__global__ __launch_bounds__(256) void sq_kernel(const float* __restrict__ f,
                                                 float* __restrict__ sq) {
    const int wave = threadIdx.x >> 6;
    const int lane = threadIdx.x & 63;
    const int row  = blockIdx.x * 4 + wave;
    const float4* rp = reinterpret_cast<const float4*>(f + (size_t)row * Cc);
    float4 v0 = rp[lane * 2 + 0];
    float4 v1 = rp[lane * 2 + 1];
    float s = v0.x * v0.x + v0.y * v0.y + v0.z * v0.z + v0.w * v0.w +
              v1.x * v1.x + v1.y * v1.y + v1.z * v1.z + v1.w * v1.w;
    #pragma unroll
    for (int off = 32; off > 0; off >>= 1) s += __shfl_down(s, off, 64);
    if (lane == 0) sq[row] = s;
}

__global__ __launch_bounds__(256) void pair_fp32(const float* __restrict__ f,
                                                 const int* __restrict__ tgt,
                                                 const float* __restrict__ sq,
                                                 double* __restrict__ partials) {
    int rem = blockIdx.x, br = 0;
    while (rem >= NBLK1 - br) { rem -= NBLK1 - br; ++br; }
    const int bc = br + rem;

    __shared__ float As[BK1][LSTR];
    __shared__ float Bs[BK1][LSTR];
    __shared__ float red[256];

    const int tid  = threadIdx.x;
    const int tx   = tid & 15;
    const int ty   = tid >> 4;
    const int row0 = ty * 4;
    const int col0 = tx * 4;

    const float* abase = f + (size_t)br * BM1 * Cc;
    const float* bbase = f + (size_t)bc * BM1 * Cc;

    const int r0 = tid >> 3;
    const int kb = (tid & 7) * 4;

    float acc[4][4] = {};

    for (int k0 = 0; k0 < Cc; k0 += BK1) {
        float4 a0 = *reinterpret_cast<const float4*>(abase + (size_t)(r0)      * Cc + k0 + kb);
        float4 a1 = *reinterpret_cast<const float4*>(abase + (size_t)(r0 + 32) * Cc + k0 + kb);
        float4 b0 = *reinterpret_cast<const float4*>(bbase + (size_t)(r0)      * Cc + k0 + kb);
        float4 b1 = *reinterpret_cast<const float4*>(bbase + (size_t)(r0 + 32) * Cc + k0 + kb);
        __syncthreads();
        As[kb + 0][r0]      = a0.x; As[kb + 1][r0]      = a0.y;
        As[kb + 2][r0]      = a0.z; As[kb + 3][r0]      = a0.w;
        As[kb + 0][r0 + 32] = a1.x; As[kb + 1][r0 + 32] = a1.y;
        As[kb + 2][r0 + 32] = a1.z; As[kb + 3][r0 + 32] = a1.w;
        Bs[kb + 0][r0]      = b0.x; Bs[kb + 1][r0]      = b0.y;
        Bs[kb + 2][r0]      = b0.z; Bs[kb + 3][r0]      = b0.w;
        Bs[kb + 0][r0 + 32] = b1.x; Bs[kb + 1][r0 + 32] = b1.y;
        Bs[kb + 2][r0 + 32] = b1.z; Bs[kb + 3][r0 + 32] = b1.w;
        __syncthreads();
        #pragma unroll
        for (int k = 0; k < BK1; ++k) {
            float4 av = *reinterpret_cast<const float4*>(&As[k][row0]);
            float4 bv = *reinterpret_cast<const float4*>(&Bs[k][col0]);
            acc[0][0] = fmaf(av.x, bv.x, acc[0][0]);
            acc[0][1] = fmaf(av.x, bv.y, acc[0][1]);
            acc[0][2] = fmaf(av.x, bv.z, acc[0][2]);
            acc[0][3] = fmaf(av.x, bv.w, acc[0][3]);
            acc[1][0] = fmaf(av.y, bv.x, acc[1][0]);
            acc[1][1] = fmaf(av.y, bv.y, acc[1][1]);
            acc[1][2] = fmaf(av.y, bv.z, acc[1][2]);
            acc[1][3] = fmaf(av.y, bv.w, acc[1][3]);
            acc[2][0] = fmaf(av.z, bv.x, acc[2][0]);
            acc[2][1] = fmaf(av.z, bv.y, acc[2][1]);
            acc[2][2] = fmaf(av.z, bv.z, acc[2][2]);
            acc[2][3] = fmaf(av.z, bv.w, acc[2][3]);
            acc[3][0] = fmaf(av.w, bv.x, acc[3][0]);
            acc[3][1] = fmaf(av.w, bv.y, acc[3][1]);
            acc[3][2] = fmaf(av.w, bv.z, acc[3][2]);
            acc[3][3] = fmaf(av.w, bv.w, acc[3][3]);
        }
    }

    const int gi = br * BM1 + row0;
    const int gj = bc * BM1 + col0;
    float sqi[4], sqj[4];
    int   ti_[4], tj_[4];
    #pragma unroll
    for (int m = 0; m < 4; ++m) { sqi[m] = sq[gi + m]; ti_[m] = tgt[gi + m]; }
    #pragma unroll
    for (int n = 0; n < 4; ++n) { sqj[n] = sq[gj + n]; tj_[n] = tgt[gj + n]; }

    float pos = 0.f, neg = 0.f;
    #pragma unroll
    for (int m = 0; m < 4; ++m)
        #pragma unroll
        for (int n = 0; n < 4; ++n) {
            if (gi + m == gj + n) continue;
            float d = fmaxf(sqi[m] + sqj[n] - 2.0f * acc[m][n], 0.0f);
            if (ti_[m] == tj_[n]) pos += d;
            else if (d < 1.0f) { float t = MRG - sqrtf(d); neg += t * t; }
        }
    const float w = (br == bc) ? 1.0f : 2.0f;
    red[tid] = w * (pos + neg);
    __syncthreads();
    #pragma unroll
    for (int st = 128; st > 0; st >>= 1) {
        if (tid < st) red[tid] += red[tid + st];
        __syncthreads();
    }
    if (tid == 0) partials[blockIdx.x] = (double)red[0];
}

// ---------------------------------------------------------------- final reduction
__global__ __launch_bounds__(256) void finish_kernel(const double* __restrict__ partials,
                                                     float* __restrict__ out, int n) {
    __shared__ double red[256];
    double s = 0.0;
    for (int i = threadIdx.x; i < n; i += 256) s += partials[i];
    red[threadIdx.x] = s;
    __syncthreads();
    #pragma unroll
    for (int st = 128; st > 0; st >>= 1) {
        if (threadIdx.x < st) red[threadIdx.x] += red[threadIdx.x + st];
        __syncthreads();
    }
    if (threadIdx.x == 0) {
        const double t = (double)Nn * (double)(Nn - 1);
        out[0] = (float)(red[0] / (2.0 * t));
    }
}

// ---------------------------------------------------------------- launch
extern "C" void kernel_launch(void* const* d_in, const int* in_sizes, int n_in,
                              void* d_out, int out_size, void* d_ws, size_t ws_size,
                              hipStream_t stream) {
    const float* f   = (const float*)d_in[0];
    const int*   tgt = (const int*)d_in[1];
    float*       out = (float*)d_out;

    const size_t fbBytes = (size_t)Nn * Cc * 2;           // 8 MB bf16 copy
    const size_t sqBytes = (size_t)Nn * sizeof(float);    // 32 KB
    const size_t needed  = fbBytes + sqBytes + (size_t)NPAIRS2 * sizeof(double);

    if (ws_size >= needed) {
        unsigned short* fb = (unsigned short*)d_ws;
        float*  sq         = (float*)((char*)d_ws + fbBytes);
        double* partials   = (double*)((char*)d_ws + fbBytes + sqBytes);

        hipLaunchKernelGGL(cvtsq_kernel,  dim3(Nn / 4),  dim3(256), 0, stream, f, fb, sq);
        hipLaunchKernelGGL(pair_mfma,     dim3(NPAIRS2), dim3(256), 0, stream, fb, tgt, sq, partials);
        hipLaunchKernelGGL(finish_kernel, dim3(1),       dim3(256), 0, stream, partials, out, NPAIRS2);
    } else {
        float*  sq       = (float*)d_ws;
        double* partials = (double*)((char*)d_ws + sqBytes);

        hipLaunchKernelGGL(sq_kernel,     dim3(Nn / 4),  dim3(256), 0, stream, f, sq);
        hipLaunchKernelGGL(pair_fp32,     dim3(NPAIRS1), dim3(256), 0, stream, f, tgt, sq, partials);
        hipLaunchKernelGGL(finish_kernel, dim3(1),       dim3(256), 0, stream, partials, out, NPAIRS1);
    }
}

// Round 4
// 93.295 us; speedup vs baseline: 1.0176x; 1.0176x over previous
//
#include <hip/hip_runtime.h>
#include <math.h>
#include <stdint.h>

// ContrastiveLoss: N=8192, C=512, NC=100, MARGIN=1.0
// loss = (sum_{i!=j,same} d_ij + sum_{i!=j,diff} max(0, 1-sqrt(d_ij))^2) / (2*N*(N-1))
// d_ij = |xi|^2+|xj|^2-2 xi.xj (clamped at 0).
//
// Round 4: algebraic restructure.
//  positive = sum_c [ 2 n_c S2_c - 2 |M_c|^2 ]   (class sums, O(N*C), fp64)
//  negative: hinge active only when d<1. Screen all pairs with a 32-feature
//  partial distance (bf16 MFMA, lower bound on d, threshold 2.0 covers bf16
//  rounding); exact fp32 recompute for the (essentially zero) candidates.
//  Fully deterministic: no atomics, fixed reduction orders.

static constexpr int   Nn  = 8192;
static constexpr int   Cc  = 512;
static constexpr float MRG = 1.0f;
static constexpr int   KF  = 32;          // filter features
static constexpr float FILT_THR = 2.0f;   // 1.0 margin^2 + bf16-error slack

static constexpr int NBLK2   = Nn / 128;                  // 64
static constexpr int NPAIRS2 = NBLK2 * (NBLK2 + 1) / 2;   // 2080
static constexpr int NCHUNK  = 32;                        // row chunks (256 rows each)
static constexpr int NCLS    = 100;

// ---- fp32 fallback config (round 1, small-ws path) ----
static constexpr int BM1     = 64;
static constexpr int BK1     = 32;
static constexpr int NBLK1   = Nn / BM1;
static constexpr int NPAIRS1 = NBLK1 * (NBLK1 + 1) / 2;
static constexpr int LSTR    = 68;

typedef __attribute__((ext_vector_type(8))) short short8v;
typedef __attribute__((ext_vector_type(4))) float f32x4;

static __device__ inline unsigned short f2bf(float x) {
    unsigned u = __float_as_uint(x);
    unsigned rnd = 0x7FFFu + ((u >> 16) & 1u);
    return (unsigned short)((u + rnd) >> 16);
}

// ---------------------------------------------------------------- prep: sq, sq32, bf16[0:32)
__global__ __launch_bounds__(256) void prep_kernel(const float* __restrict__ f,
                                                   unsigned short* __restrict__ fb32,
                                                   float* __restrict__ sq,
                                                   float* __restrict__ sq32) {
    const int wave = threadIdx.x >> 6;
    const int lane = threadIdx.x & 63;
    const int row  = blockIdx.x * 4 + wave;
    const float4* rp = reinterpret_cast<const float4*>(f + (size_t)row * Cc);
    float4 v0 = rp[lane * 2 + 0];
    float4 v1 = rp[lane * 2 + 1];
    float s8 = v0.x * v0.x + v0.y * v0.y + v0.z * v0.z + v0.w * v0.w +
               v1.x * v1.x + v1.y * v1.y + v1.z * v1.z + v1.w * v1.w;
    if (lane < 4) {   // first 32 features -> bf16
        short8v o;
        o[0] = (short)f2bf(v0.x); o[1] = (short)f2bf(v0.y);
        o[2] = (short)f2bf(v0.z); o[3] = (short)f2bf(v0.w);
        o[4] = (short)f2bf(v1.x); o[5] = (short)f2bf(v1.y);
        o[6] = (short)f2bf(v1.z); o[7] = (short)f2bf(v1.w);
        *reinterpret_cast<short8v*>(fb32 + (size_t)row * KF + lane * 8) = o;
    }
    float sAll = s8;
    float s32  = (lane < 4) ? s8 : 0.0f;
    #pragma unroll
    for (int off = 32; off > 0; off >>= 1) {
        sAll += __shfl_down(sAll, off, 64);
        s32  += __shfl_down(s32,  off, 64);
    }
    if (lane == 0) { sq[row] = sAll; sq32[row] = s32; }
}

// ---------------------------------------------------------------- class feature sums (deterministic)
// block (chunk, quarter): 128 threads; thread t owns dim quarter*128+t.
// bins[c][t] accumulated race-free (only thread t writes column t).
__global__ __launch_bounds__(128) void clspart_kernel(const float* __restrict__ f,
                                                      const int* __restrict__ tgt,
                                                      float* __restrict__ clsPart) {
    const int chunk   = blockIdx.x;   // 0..31
    const int quarter = blockIdx.y;   // 0..3
    const int t       = threadIdx.x;  // 0..127
    __shared__ float bins[NCLS][128];
    for (int i = t; i < NCLS * 128; i += 128) ((float*)bins)[i] = 0.0f;
    __syncthreads();
    const int r0 = chunk * 256;
    for (int i = 0; i < 256; ++i) {
        const int   c = tgt[r0 + i];
        const float x = f[(size_t)(r0 + i) * Cc + quarter * 128 + t];
        bins[c][t] += x;
    }
    __syncthreads();
    for (int c = 0; c < NCLS; ++c)
        clsPart[((size_t)chunk * NCLS + c) * Cc + quarter * 128 + t] = bins[c][t];
}

// ---------------------------------------------------------------- per-class counts + S2 (deterministic)
__global__ __launch_bounds__(128) void cnts2_kernel(const int* __restrict__ tgt,
                                                    const float* __restrict__ sq,
                                                    int* __restrict__ cntPart,
                                                    double* __restrict__ s2Part) {
    const int chunk = blockIdx.x;
    const int t     = threadIdx.x;    // class id (t<100 active)
    int cnt = 0; double s2 = 0.0;
    const int r0 = chunk * 256;
    for (int i = 0; i < 256; ++i) {
        const int   c = tgt[r0 + i];
        const float s = sq[r0 + i];
        if (c == t) { cnt++; s2 += (double)s; }
    }
    if (t < NCLS) { cntPart[chunk * NCLS + t] = cnt; s2Part[chunk * NCLS + t] = s2; }
}

// ---------------------------------------------------------------- sum_c |M_c|^2 partials
__global__ __launch_bounds__(256) void msq_kernel(const float* __restrict__ clsPart,
                                                  double* __restrict__ msqPart) {
    __shared__ double red[256];
    double local = 0.0;
    const int base = blockIdx.x * 800;            // 64 blocks x 800 = 51200 bins
    #pragma unroll
    for (int it = 0; it < 4; ++it) {
        const int idx = base + it * 256 + threadIdx.x;   // idx = c*512 + d
        if (idx < base + 800) {
            float s = 0.0f;
            #pragma unroll 4
            for (int ch = 0; ch < NCHUNK; ++ch)
                s += clsPart[(size_t)ch * NCLS * Cc + idx];
            local += (double)s * (double)s;
        }
    }
    red[threadIdx.x] = local;
    __syncthreads();
    #pragma unroll
    for (int st = 128; st > 0; st >>= 1) {
        if (threadIdx.x < st) red[threadIdx.x] += red[threadIdx.x + st];
        __syncthreads();
    }
    if (threadIdx.x == 0) msqPart[blockIdx.x] = red[0];
}

// ---------------------------------------------------------------- hinge screen (K=32 bf16 MFMA)
__global__ __launch_bounds__(256) void filter_kernel(const unsigned short* __restrict__ fb32,
                                                     const float* __restrict__ f,
                                                     const int* __restrict__ tgt,
                                                     const float* __restrict__ sq32,
                                                     double* __restrict__ negPart) {
    int rem = blockIdx.x, br = 0;
    while (rem >= NBLK2 - br) { rem -= NBLK2 - br; ++br; }
    const int bc = br + rem;

    __shared__ unsigned short As[128][40];   // 80B row stride: bank-spread, 16B aligned
    __shared__ unsigned short Bs[128][40];

    const int tid  = threadIdx.x;
    const int lane = tid & 63;
    const int wid  = tid >> 6;
    const int wr   = wid >> 1;
    const int wc   = wid & 1;

    #pragma unroll
    for (int it = 0; it < 2; ++it) {
        const int s   = tid + it * 256;     // 512 slots of 16B
        const int row = s >> 2, q = s & 3;
        short8v va = *reinterpret_cast<const short8v*>(fb32 + (size_t)(br * 128 + row) * KF + q * 8);
        short8v vb = *reinterpret_cast<const short8v*>(fb32 + (size_t)(bc * 128 + row) * KF + q * 8);
        *reinterpret_cast<short8v*>(&As[row][q * 8]) = va;
        *reinterpret_cast<short8v*>(&Bs[row][q * 8]) = vb;
    }
    __syncthreads();

    const f32x4 zero = {0.f, 0.f, 0.f, 0.f};
    short8v a[4], b[4];
    #pragma unroll
    for (int mf = 0; mf < 4; ++mf) {
        const int row = wr * 64 + mf * 16 + (lane & 15);
        a[mf] = *reinterpret_cast<const short8v*>(&As[row][(lane >> 4) * 8]);
    }
    #pragma unroll
    for (int nf = 0; nf < 4; ++nf) {
        const int row = wc * 64 + nf * 16 + (lane & 15);
        b[nf] = *reinterpret_cast<const short8v*>(&Bs[row][(lane >> 4) * 8]);
    }
    f32x4 acc[4][4];
    #pragma unroll
    for (int mf = 0; mf < 4; ++mf)
        #pragma unroll
        for (int nf = 0; nf < 4; ++nf)
            acc[mf][nf] = __builtin_amdgcn_mfma_f32_16x16x32_bf16(a[mf], b[nf], zero, 0, 0, 0);

    // epilogue: d32 lower bound; exact recompute for rare candidates
    const int gi0 = br * 128 + wr * 64;
    const int gj0 = bc * 128 + wc * 64;

    float s32i[16]; int ti[16];
    #pragma unroll
    for (int mf = 0; mf < 4; ++mf)
        #pragma unroll
        for (int j = 0; j < 4; ++j) {
            const int r = gi0 + mf * 16 + (lane >> 4) * 4 + j;
            s32i[mf * 4 + j] = sq32[r];
            ti[mf * 4 + j]   = tgt[r];
        }
    float s32j[4]; int tj[4];
    #pragma unroll
    for (int nf = 0; nf < 4; ++nf) {
        const int c = gj0 + nf * 16 + (lane & 15);
        s32j[nf] = sq32[c];
        tj[nf]   = tgt[c];
    }

    float neg = 0.0f;
    #pragma unroll
    for (int mf = 0; mf < 4; ++mf)
        #pragma unroll
        for (int nf = 0; nf < 4; ++nf)
            #pragma unroll
            for (int j = 0; j < 4; ++j) {
                const int r = gi0 + mf * 16 + (lane >> 4) * 4 + j;
                const int c = gj0 + nf * 16 + (lane & 15);
                const float d32 = s32i[mf * 4 + j] + s32j[nf] - 2.0f * acc[mf][nf][j];
                if (r != c && ti[mf * 4 + j] != tj[nf] && d32 < FILT_THR) {
                    // exact full distance (fp32), rare path
                    const float4* xr = reinterpret_cast<const float4*>(f + (size_t)r * Cc);
                    const float4* xc = reinterpret_cast<const float4*>(f + (size_t)c * Cc);
                    float dd = 0.0f;
                    for (int k = 0; k < Cc / 4; ++k) {
                        float4 aa = xr[k], bb = xc[k];
                        float dx = aa.x - bb.x, dy = aa.y - bb.y;
                        float dz = aa.z - bb.z, dw = aa.w - bb.w;
                        dd += dx * dx + dy * dy + dz * dz + dw * dw;
                    }
                    const float t = (dd > 0.0f) ? (MRG - sqrtf(dd)) : MRG;
                    if (t > 0.0f) neg += t * t;
                }
            }

    __syncthreads();
    float* red = reinterpret_cast<float*>(As);
    const float w = (br == bc) ? 1.0f : 2.0f;
    red[tid] = w * neg;
    __syncthreads();
    #pragma unroll
    for (int st = 128; st > 0; st >>= 1) {
        if (tid < st) red[tid] += red[tid + st];
        __syncthreads();
    }
    if (tid == 0) negPart[blockIdx.x] = (double)red[0];
}

// ---------------------------------------------------------------- final combine
__global__ __launch_bounds__(256) void finish2_kernel(const int* __restrict__ cntPart,
                                                      const double* __restrict__ s2Part,
                                                      const double* __restrict__ msqPart,
                                                      const double* __restrict__ negPart,
                                                      float* __restrict__ out) {
    __shared__ double red[256];
    const int t = threadIdx.x;
    double pa = 0.0;
    if (t < NCLS) {
        long  n  = 0;
        double s2 = 0.0;
        for (int ch = 0; ch < NCHUNK; ++ch) {
            n  += cntPart[ch * NCLS + t];
            s2 += s2Part[ch * NCLS + t];
        }
        pa = 2.0 * (double)n * s2;
    }
    double msum = (t < 64) ? msqPart[t] : 0.0;
    double nsum = 0.0;
    for (int i = t; i < NPAIRS2; i += 256) nsum += negPart[i];
    red[t] = pa - 2.0 * msum + nsum;
    __syncthreads();
    #pragma unroll
    for (int st = 128; st > 0; st >>= 1) {
        if (t < st) red[t] += red[t + st];
        __syncthreads();
    }
    if (t == 0) {
        const double T = (double)Nn * (double)(Nn - 1);
        out[0] = (float)(red[0] / (2.0 * T));
    }
}

// ---------------------------------------------------------------- fp32 fallback (round 1)
__global__ __launch_bounds__(256) void sq_kernel(const float* __restrict__ f,
                                                 float* __restrict__ sq) {
    const int wave = threadIdx.x >> 6;
    const int lane = threadIdx.x & 63;
    const int row  = blockIdx.x * 4 + wave;
    const float4* rp = reinterpret_cast<const float4*>(f + (size_t)row * Cc);
    float4 v0 = rp[lane * 2 + 0];
    float4 v1 = rp[lane * 2 + 1];
    float s = v0.x * v0.x + v0.y * v0.y + v0.z * v0.z + v0.w * v0.w +
              v1.x * v1.x + v1.y * v1.y + v1.z * v1.z + v1.w * v1.w;
    #pragma unroll
    for (int off = 32; off > 0; off >>= 1) s += __shfl_down(s, off, 64);
    if (lane == 0) sq[row] = s;
}

__global__ __launch_bounds__(256) void pair_fp32(const float* __restrict__ f,
                                                 const int* __restrict__ tgt,
                                                 const float* __restrict__ sq,
                                                 double* __restrict__ partials) {
    int rem = blockIdx.x, br = 0;
    while (rem >= NBLK1 - br) { rem -= NBLK1 - br; ++br; }
    const int bc = br + rem;

    __shared__ float As[BK1][LSTR];
    __shared__ float Bs[BK1][LSTR];
    __shared__ float red[256];

    const int tid  = threadIdx.x;
    const int tx   = tid & 15;
    const int ty   = tid >> 4;
    const int row0 = ty * 4;
    const int col0 = tx * 4;

    const float* abase = f + (size_t)br * BM1 * Cc;
    const float* bbase = f + (size_t)bc * BM1 * Cc;

    const int r0 = tid >> 3;
    const int kb = (tid & 7) * 4;

    float acc[4][4] = {};

    for (int k0 = 0; k0 < Cc; k0 += BK1) {
        float4 a0 = *reinterpret_cast<const float4*>(abase + (size_t)(r0)      * Cc + k0 + kb);
        float4 a1 = *reinterpret_cast<const float4*>(abase + (size_t)(r0 + 32) * Cc + k0 + kb);
        float4 b0 = *reinterpret_cast<const float4*>(bbase + (size_t)(r0)      * Cc + k0 + kb);
        float4 b1 = *reinterpret_cast<const float4*>(bbase + (size_t)(r0 + 32) * Cc + k0 + kb);
        __syncthreads();
        As[kb + 0][r0]      = a0.x; As[kb + 1][r0]      = a0.y;
        As[kb + 2][r0]      = a0.z; As[kb + 3][r0]      = a0.w;
        As[kb + 0][r0 + 32] = a1.x; As[kb + 1][r0 + 32] = a1.y;
        As[kb + 2][r0 + 32] = a1.z; As[kb + 3][r0 + 32] = a1.w;
        Bs[kb + 0][r0]      = b0.x; Bs[kb + 1][r0]      = b0.y;
        Bs[kb + 2][r0]      = b0.z; Bs[kb + 3][r0]      = b0.w;
        Bs[kb + 0][r0 + 32] = b1.x; Bs[kb + 1][r0 + 32] = b1.y;
        Bs[kb + 2][r0 + 32] = b1.z; Bs[kb + 3][r0 + 32] = b1.w;
        __syncthreads();
        #pragma unroll
        for (int k = 0; k < BK1; ++k) {
            float4 av = *reinterpret_cast<const float4*>(&As[k][row0]);
            float4 bv = *reinterpret_cast<const float4*>(&Bs[k][col0]);
            acc[0][0] = fmaf(av.x, bv.x, acc[0][0]);
            acc[0][1] = fmaf(av.x, bv.y, acc[0][1]);
            acc[0][2] = fmaf(av.x, bv.z, acc[0][2]);
            acc[0][3] = fmaf(av.x, bv.w, acc[0][3]);
            acc[1][0] = fmaf(av.y, bv.x, acc[1][0]);
            acc[1][1] = fmaf(av.y, bv.y, acc[1][1]);
            acc[1][2] = fmaf(av.y, bv.z, acc[1][2]);
            acc[1][3] = fmaf(av.y, bv.w, acc[1][3]);
            acc[2][0] = fmaf(av.z, bv.x, acc[2][0]);
            acc[2][1] = fmaf(av.z, bv.y, acc[2][1]);
            acc[2][2] = fmaf(av.z, bv.z, acc[2][2]);
            acc[2][3] = fmaf(av.z, bv.w, acc[2][3]);
            acc[3][0] = fmaf(av.w, bv.x, acc[3][0]);
            acc[3][1] = fmaf(av.w, bv.y, acc[3][1]);
            acc[3][2] = fmaf(av.w, bv.z, acc[3][2]);
            acc[3][3] = fmaf(av.w, bv.w, acc[3][3]);
        }
    }

    const int gi = br * BM1 + row0;
    const int gj = bc * BM1 + col0;
    float sqi[4], sqj[4];
    int   ti_[4], tj_[4];
    #pragma unroll
    for (int m = 0; m < 4; ++m) { sqi[m] = sq[gi + m]; ti_[m] = tgt[gi + m]; }
    #pragma unroll
    for (int n = 0; n < 4; ++n) { sqj[n] = sq[gj + n]; tj_[n] = tgt[gj + n]; }

    float pos = 0.f, neg = 0.f;
    #pragma unroll
    for (int m = 0; m < 4; ++m)
        #pragma unroll
        for (int n = 0; n < 4; ++n) {
            if (gi + m == gj + n) continue;
            float d = fmaxf(sqi[m] + sqj[n] - 2.0f * acc[m][n], 0.0f);
            if (ti_[m] == tj_[n]) pos += d;
            else if (d < 1.0f) { float t = MRG - sqrtf(d); neg += t * t; }
        }
    const float w = (br == bc) ? 1.0f : 2.0f;
    red[tid] = w * (pos + neg);
    __syncthreads();
    #pragma unroll
    for (int st = 128; st > 0; st >>= 1) {
        if (tid < st) red[tid] += red[tid + st];
        __syncthreads();
    }
    if (tid == 0) partials[blockIdx.x] = (double)red[0];
}

__global__ __launch_bounds__(256) void finish_kernel(const double* __restrict__ partials,
                                                     float* __restrict__ out, int n) {
    __shared__ double red[256];
    double s = 0.0;
    for (int i = threadIdx.x; i < n; i += 256) s += partials[i];
    red[threadIdx.x] = s;
    __syncthreads();
    #pragma unroll
    for (int st = 128; st > 0; st >>= 1) {
        if (threadIdx.x < st) red[threadIdx.x] += red[threadIdx.x + st];
        __syncthreads();
    }
    if (threadIdx.x == 0) {
        const double t = (double)Nn * (double)(Nn - 1);
        out[0] = (float)(red[0] / (2.0 * t));
    }
}

// ---------------------------------------------------------------- launch
extern "C" void kernel_launch(void* const* d_in, const int* in_sizes, int n_in,
                              void* d_out, int out_size, void* d_ws, size_t ws_size,
                              hipStream_t stream) {
    const float* f   = (const float*)d_in[0];
    const int*   tgt = (const int*)d_in[1];
    float*       out = (float*)d_out;

    // workspace layout (all 16B-aligned)
    const size_t off_fb32 = 0;                                   // 8192*32*2   = 512 KB
    const size_t off_sq   = off_fb32 + (size_t)Nn * KF * 2;      // 32 KB
    const size_t off_sq32 = off_sq   + (size_t)Nn * 4;           // 32 KB
    const size_t off_cls  = off_sq32 + (size_t)Nn * 4;           // 32*100*512*4 = 6.55 MB
    const size_t off_cnt  = off_cls  + (size_t)NCHUNK * NCLS * Cc * 4;
    const size_t off_s2   = off_cnt  + (size_t)NCHUNK * NCLS * 4;
    const size_t off_msq  = off_s2   + (size_t)NCHUNK * NCLS * 8;
    const size_t off_neg  = off_msq  + (size_t)64 * 8;
    const size_t needed   = off_neg  + (size_t)NPAIRS2 * 8;      // ~7.2 MB

    if (ws_size >= needed) {
        unsigned short* fb32   = (unsigned short*)((char*)d_ws + off_fb32);
        float*  sq             = (float*) ((char*)d_ws + off_sq);
        float*  sq32           = (float*) ((char*)d_ws + off_sq32);
        float*  clsPart        = (float*) ((char*)d_ws + off_cls);
        int*    cntPart        = (int*)   ((char*)d_ws + off_cnt);
        double* s2Part         = (double*)((char*)d_ws + off_s2);
        double* msqPart        = (double*)((char*)d_ws + off_msq);
        double* negPart        = (double*)((char*)d_ws + off_neg);

        hipLaunchKernelGGL(prep_kernel,    dim3(Nn / 4),        dim3(256), 0, stream, f, fb32, sq, sq32);
        hipLaunchKernelGGL(clspart_kernel, dim3(NCHUNK, 4),     dim3(128), 0, stream, f, tgt, clsPart);
        hipLaunchKernelGGL(cnts2_kernel,   dim3(NCHUNK),        dim3(128), 0, stream, tgt, sq, cntPart, s2Part);
        hipLaunchKernelGGL(filter_kernel,  dim3(NPAIRS2),       dim3(256), 0, stream, fb32, f, tgt, sq32, negPart);
        hipLaunchKernelGGL(msq_kernel,     dim3(64),            dim3(256), 0, stream, clsPart, msqPart);
        hipLaunchKernelGGL(finish2_kernel, dim3(1),             dim3(256), 0, stream, cntPart, s2Part, msqPart, negPart, out);
    } else {
        float*  sq       = (float*)d_ws;
        double* partials = (double*)((char*)d_ws + (size_t)Nn * sizeof(float));

        hipLaunchKernelGGL(sq_kernel,     dim3(Nn / 4),  dim3(256), 0, stream, f, sq);
        hipLaunchKernelGGL(pair_fp32,     dim3(NPAIRS1), dim3(256), 0, stream, f, tgt, sq, partials);
        hipLaunchKernelGGL(finish_kernel, dim3(1),       dim3(256), 0, stream, partials, out, NPAIRS1);
    }
}